// Round 6
// baseline (226.073 us; speedup 1.0000x reference)
//
#include <hip/hip_runtime.h>
#include <math.h>

#define SP 32768            // 32*32*32 voxels
#define PW 38               // padded volume width (zero ring around 34^3 logical)
#define PW2 (PW*PW)         // 1444
#define PVOX (PW*PW*PW)     // 54872

typedef short bf16x8 __attribute__((ext_vector_type(8)));
typedef short s16x4 __attribute__((ext_vector_type(4)));
typedef float f32x4 __attribute__((ext_vector_type(4)));

__device__ __forceinline__ unsigned short f2b(float f) {
    unsigned u = __float_as_uint(f);
    u = (u + 0x7FFFu + ((u >> 16) & 1u)) >> 16;   // RNE
    return (unsigned short)u;
}

// ================= K1: prep (bf16 B^T weights) + x transpose + dwconv ==============
__global__ void k_front(const float* __restrict__ x, const float* __restrict__ dw,
                        const float* __restrict__ off_w, const float* __restrict__ mask_w,
                        const float* __restrict__ off_b, const float* __restrict__ mask_b,
                        const float* __restrict__ inp_w, const float* __restrict__ out_w,
                        unsigned short* __restrict__ WcatB, float* __restrict__ bcat,
                        unsigned short* __restrict__ inpB, unsigned short* __restrict__ outB,
                        unsigned short* __restrict__ x_tb,
                        float* __restrict__ xc, float* __restrict__ partials) {
    int bb = blockIdx.x, tid = threadIdx.x;
    if (bb < 88) {                               // ---- weight prep ----
        int idx = bb * 256 + tid;
        int j = idx >> 6, k = idx & 63;
        if (j < 224) {
            float v = 0.f;
            if (j < 162) v = off_w[k * 162 + j];
            else if (j < 216) v = mask_w[k * 54 + (j - 162)];
            WcatB[j * 64 + k] = f2b(v);
            if (k == 0) bcat[j] = (j < 162) ? off_b[j] : (j < 216 ? mask_b[j - 162] : 0.f);
        } else if (j < 288) {
            outB[(j - 224) * 64 + k] = f2b(out_w[k * 64 + (j - 224)]);
        } else {
            inpB[(j - 288) * 64 + k] = f2b(inp_w[k * 64 + (j - 288)]);
        }
        return;
    }
    if (bb < 600) {                              // ---- x: NCDHW -> [s][c] bf16 ----
        __shared__ unsigned short tile[64][66];
        int s0 = (bb - 88) * 64;
        int row = tid >> 6, lane = tid & 63;
        for (int c = row; c < 64; c += 4)
            tile[c][lane] = f2b(x[(size_t)c * SP + s0 + lane]);
        __syncthreads();
        for (int r = row; r < 64; r += 4)
            x_tb[(size_t)(s0 + r) * 64 + lane] = tile[lane][r];
        return;
    }
    // ---- depthwise conv 3x3x3 + per-block sum/sumsq ----
    int b3 = bb - 600;
    int e = b3 * 256 + tid;
    int c = e >> 15, s = e & 32767;
    int d = s >> 10, h = (s >> 5) & 31, w = s & 31;
    const float* xs = x + (size_t)c * SP;
    const float* wt = dw + c * 27;
    float a = 0.f;
#pragma unroll
    for (int kd = 0; kd < 3; ++kd) {
        int zz = d + kd - 1; if ((unsigned)zz >= 32u) continue;
#pragma unroll
        for (int kh = 0; kh < 3; ++kh) {
            int yy = h + kh - 1; if ((unsigned)yy >= 32u) continue;
#pragma unroll
            for (int kw = 0; kw < 3; ++kw) {
                int xx = w + kw - 1; if ((unsigned)xx >= 32u) continue;
                a += xs[(zz << 10) + (yy << 5) + xx] * wt[kd * 9 + kh * 3 + kw];
            }
        }
    }
    xc[e] = a;
    __shared__ float rs[256], rq[256];
    rs[tid] = a; rq[tid] = a * a;
    __syncthreads();
    for (int off = 128; off > 0; off >>= 1) {
        if (tid < off) { rs[tid] += rs[tid + off]; rq[tid] += rq[tid + off]; }
        __syncthreads();
    }
    if (tid == 0) {
        partials[b3 * 2 + 0] = rs[0];
        partials[b3 * 2 + 1] = rq[0];
    }
}

// ========= K2: GN+GELU -> x1b  |  MFMA inproj -> xpad interior  |  ring zero =========
// Three independent jobs (all depend only on K1), disjoint writes.
__global__ void k_mid(const float* __restrict__ xc, const float* __restrict__ partials,
                      const float* __restrict__ gn_w, const float* __restrict__ gn_b,
                      unsigned short* __restrict__ x1b,
                      const unsigned short* __restrict__ x_tb,
                      const unsigned short* __restrict__ inpB,
                      const float* __restrict__ inp_b,
                      float* __restrict__ xpad) {
    int bb = blockIdx.x, tid = threadIdx.x;
    if (bb < 512) {                              // ---- GroupNorm(1,C)+GELU, transposed ----
        __shared__ float rs[256], rq[256];
        __shared__ unsigned short tile[64][66];
        float a = 0.f, b = 0.f;
        for (int i = tid; i < 8192; i += 256) { a += partials[2 * i]; b += partials[2 * i + 1]; }
        rs[tid] = a; rq[tid] = b;
        __syncthreads();
        for (int off = 128; off > 0; off >>= 1) {
            if (tid < off) { rs[tid] += rs[tid + off]; rq[tid] += rq[tid + off]; }
            __syncthreads();
        }
        const float Minv = 1.f / 2097152.f;
        float mu = rs[0] * Minv;
        float var = rq[0] * Minv - mu * mu;
        float rsq = rsqrtf(var + 1e-5f);
        int s0 = bb * 64;
        int row = tid >> 6, lane = tid & 63;
        for (int c = row; c < 64; c += 4) {
            float v = (xc[(size_t)c * SP + s0 + lane] - mu) * rsq * gn_w[c] + gn_b[c];
            float t = tanhf(0.7978845608028654f * (v + 0.044715f * v * v * v));
            tile[c][lane] = f2b(0.5f * v * (1.f + t));
        }
        __syncthreads();
        for (int r = row; r < 64; r += 4)
            x1b[(size_t)(s0 + r) * 64 + lane] = tile[lane][r];
        return;
    }
    if (bb < 1024) {                             // ---- inproj: 4 waves x 16 voxels ----
        int wv = tid >> 6, lane = tid & 63;
        int quad = lane >> 4, col = lane & 15;
        int s0 = (bb - 512) * 64 + wv * 16;
        bf16x8 a0 = *(const bf16x8*)(x_tb + (size_t)(s0 + col) * 64 + quad * 8);
        bf16x8 a1 = *(const bf16x8*)(x_tb + (size_t)(s0 + col) * 64 + 32 + quad * 8);
        int vp[4];
#pragma unroll
        for (int r = 0; r < 4; ++r) {
            int s = s0 + (quad << 2) + r;        // orig voxel (d,h,w) at 38-coord +2
            vp[r] = (((s >> 10) + 2) * PW + ((s >> 5) & 31) + 2) * PW + (s & 31) + 2;
        }
#pragma unroll
        for (int nt = 0; nt < 4; ++nt) {
            int n0 = nt * 16;
            bf16x8 b0 = *(const bf16x8*)(inpB + (n0 + col) * 64 + quad * 8);
            bf16x8 b1 = *(const bf16x8*)(inpB + (n0 + col) * 64 + 32 + quad * 8);
            f32x4 c = {0.f, 0.f, 0.f, 0.f};
            c = __builtin_amdgcn_mfma_f32_16x16x32_bf16(a0, b0, c, 0, 0, 0);
            c = __builtin_amdgcn_mfma_f32_16x16x32_bf16(a1, b1, c, 0, 0, 0);
            float bq = inp_b[n0 + col];
#pragma unroll
            for (int r = 0; r < 4; ++r)
                xpad[(size_t)vp[r] * 64 + n0 + col] = c[r] + bq;
        }
        return;
    }
    // ---- ring zero: 16 voxels x 16 float4-slots per 256 threads, 4 iterations ----
    int cblk = bb - 1024;
    int j = tid >> 4, c4 = tid & 15;
    f32x4 z = {0.f, 0.f, 0.f, 0.f};
#pragma unroll
    for (int k = 0; k < 4; ++k) {
        int v = cblk * 64 + k * 16 + j;
        if (v >= PVOX) break;
        int zz = v / PW2, r = v - zz * PW2, yy = r / PW, xx = r - yy * PW;
        if (zz < 2 || zz > 33 || yy < 2 || yy > 33 || xx < 2 || xx > 33)
            *(f32x4*)(xpad + (size_t)v * 64 + c4 * 4) = z;
    }
}

// ========= K3: main — MFMA offsets/masks + softmax + float4 sampling + MFMA out proj =========
// 4 voxels per wave, 8192 blocks -> 32 schedulable waves/CU.
__global__ void __launch_bounds__(64, 8) k_main(const unsigned short* __restrict__ x1b,
                                                const float* __restrict__ xpad,
                                                const unsigned short* __restrict__ WcatB,
                                                const float* __restrict__ bcat,
                                                const unsigned short* __restrict__ outB,
                                                const float* __restrict__ out_b,
                                                float* __restrict__ out) {
    __shared__ float om_s[4 * 225];              // 4 voxels: 162 offsets + 54 masks (+pad)
    __shared__ unsigned short smb[4 * 72];       // sampled accum, bf16
    int lane = threadIdx.x, quad = lane >> 4, col = lane & 15;
    // XCD swizzle: blocks sharing (blk&7) land on one XCD, contiguous 4096-voxel slab
    int sb = ((blockIdx.x & 7) << 10) + (blockIdx.x >> 3);
    int s0 = sb * 4;                             // 4 voxels per wave
    // ---- offset+mask GEMM: (4x64)@(64x224); A rows 4..15 duplicate voxels 0..3 ----
    int arow = s0 + (col & 3);
    bf16x8 a0 = *(const bf16x8*)(x1b + (size_t)arow * 64 + quad * 8);
    bf16x8 a1 = *(const bf16x8*)(x1b + (size_t)arow * 64 + 32 + quad * 8);
#pragma unroll
    for (int jt = 0; jt < 14; ++jt) {
        int n0 = jt * 16;
        bf16x8 b0 = *(const bf16x8*)(WcatB + (n0 + col) * 64 + quad * 8);
        bf16x8 b1 = *(const bf16x8*)(WcatB + (n0 + col) * 64 + 32 + quad * 8);
        f32x4 c = {0.f, 0.f, 0.f, 0.f};
        c = __builtin_amdgcn_mfma_f32_16x16x32_bf16(a0, b0, c, 0, 0, 0);
        c = __builtin_amdgcn_mfma_f32_16x16x32_bf16(a1, b1, c, 0, 0, 0);
        float bb = bcat[n0 + col];
        if (quad == 0) {                         // C rows 0..3 = the 4 real voxels
#pragma unroll
            for (int r = 0; r < 4; ++r)
                om_s[r * 225 + n0 + col] = c[r] + bb;
        }
    }
    __syncthreads();
    // ---- softmax over 27 pts: 8 rows = 4 voxels x 2 groups ----
    if (lane < 8) {
        int v = lane >> 1, g = lane & 1;
        float* m = &om_s[v * 225 + 162 + g * 27];
        float mx = m[0];
#pragma unroll
        for (int p = 1; p < 27; ++p) mx = fmaxf(mx, m[p]);
        float e[27]; float sm = 0.f;
#pragma unroll
        for (int p = 0; p < 27; ++p) { e[p] = __expf(m[p] - mx); sm += e[p]; }
        float inv = 1.f / sm;
#pragma unroll
        for (int p = 0; p < 27; ++p) m[p] = e[p] * inv;
    }
    __syncthreads();
    // ---- sampling: all 4 voxels in parallel; lane = (voxel, channel-quad) ----
    int vq = lane >> 4, cq = lane & 15, gg = cq >> 3;   // 4 channels/lane
    int d = s0 >> 10, h = (s0 >> 5) & 31, w0 = s0 & 31;
    float zb = (float)(d + 1), yb = (float)(h + 1);     // 34-logical -> 38-coord is +1
    const char* volc = (const char*)xpad + cq * 16;
    {
        const float* orow = &om_s[vq * 225 + gg * 81];
        const float* mrow = &om_s[vq * 225 + 162 + gg * 27];
        float xb = (float)(w0 + vq + 1);
        f32x4 acc = {0.f, 0.f, 0.f, 0.f};
        int p = 0;
        for (int pz = 0; pz < 3; ++pz) {
#pragma unroll
            for (int py = 0; py < 3; ++py) {
#pragma unroll
                for (int px = 0; px < 3; ++px) {
                    float ox = orow[p * 3 + 0], oy = orow[p * 3 + 1], oz = orow[p * 3 + 2];
                    float mk = mrow[p];
                    float ix = __builtin_fmaf(0.25f, ox, xb + (float)px);
                    float iy = __builtin_fmaf(0.5f, oy, yb + (float)py);
                    float iz = __builtin_fmaf(0.5f, oz, zb + (float)pz);
                    // clamp to [0,36]: OOB samples land wholly in the zero ring
                    ix = fminf(fmaxf(ix, 0.f), 36.f);
                    iy = fminf(fmaxf(iy, 0.f), 36.f);
                    iz = fminf(fmaxf(iz, 0.f), 36.f);
                    float xf = floorf(ix), yf = floorf(iy), zf = floorf(iz);
                    float fx = ix - xf, fy = iy - yf, fz = iz - zf;
                    float fi = __builtin_fmaf(zf, (float)PW2, __builtin_fmaf(yf, (float)PW, xf));
                    int ib = ((int)fi) << 8;     // 256 B per voxel row
                    f32x4 v000 = *(const f32x4*)(volc + ib);
                    f32x4 v001 = *(const f32x4*)(volc + ib + 256);
                    f32x4 v010 = *(const f32x4*)(volc + ib + PW * 256);
                    f32x4 v011 = *(const f32x4*)(volc + ib + PW * 256 + 256);
                    f32x4 v100 = *(const f32x4*)(volc + ib + PW2 * 256);
                    f32x4 v101 = *(const f32x4*)(volc + ib + PW2 * 256 + 256);
                    f32x4 v110 = *(const f32x4*)(volc + ib + (PW2 + PW) * 256);
                    f32x4 v111 = *(const f32x4*)(volc + ib + (PW2 + PW) * 256 + 256);
                    float wz0 = (1.f - fz) * mk, wz1 = fz * mk;
                    float w00 = wz0 * (1.f - fy), w01 = wz0 * fy;
                    float w10 = wz1 * (1.f - fy), w11 = wz1 * fy;
                    f32x4 t00 = v000 + fx * (v001 - v000);
                    f32x4 t01 = v010 + fx * (v011 - v010);
                    f32x4 t10 = v100 + fx * (v101 - v100);
                    f32x4 t11 = v110 + fx * (v111 - v110);
                    acc += w00 * t00 + w01 * t01 + w10 * t10 + w11 * t11;
                    ++p;
                }
            }
        }
        s16x4 sb4;
        sb4[0] = (short)f2b(acc[0]); sb4[1] = (short)f2b(acc[1]);
        sb4[2] = (short)f2b(acc[2]); sb4[3] = (short)f2b(acc[3]);
        *(s16x4*)(smb + vq * 72 + cq * 4) = sb4;
    }
    __syncthreads();
    // ---- out projection: (4x64)@(64x64); A rows duplicated ----
    int orw = col & 3;
    bf16x8 oa0 = *(const bf16x8*)(smb + orw * 72 + quad * 8);
    bf16x8 oa1 = *(const bf16x8*)(smb + orw * 72 + 32 + quad * 8);
#pragma unroll
    for (int nt = 0; nt < 4; ++nt) {
        int n0 = nt * 16;
        bf16x8 b0 = *(const bf16x8*)(outB + (n0 + col) * 64 + quad * 8);
        bf16x8 b1 = *(const bf16x8*)(outB + (n0 + col) * 64 + 32 + quad * 8);
        f32x4 c = {0.f, 0.f, 0.f, 0.f};
        c = __builtin_amdgcn_mfma_f32_16x16x32_bf16(oa0, b0, c, 0, 0, 0);
        c = __builtin_amdgcn_mfma_f32_16x16x32_bf16(oa1, b1, c, 0, 0, 0);
        float bb = out_b[n0 + col];
        if (quad == 0) {
#pragma unroll
            for (int r = 0; r < 4; ++r)
                out[(size_t)(s0 + r) * 64 + n0 + col] = c[r] + bb;
        }
    }
}

extern "C" void kernel_launch(void* const* d_in, const int* in_sizes, int n_in,
                              void* d_out, int out_size, void* d_ws, size_t ws_size,
                              hipStream_t stream) {
    const float* x      = (const float*)d_in[0];
    const float* dw_w   = (const float*)d_in[1];
    const float* gn_w   = (const float*)d_in[2];
    const float* gn_b   = (const float*)d_in[3];
    const float* inp_w  = (const float*)d_in[4];
    const float* inp_b  = (const float*)d_in[5];
    const float* off_w  = (const float*)d_in[6];
    const float* off_b  = (const float*)d_in[7];
    const float* mask_w = (const float*)d_in[8];
    const float* mask_b = (const float*)d_in[9];
    const float* out_w  = (const float*)d_in[10];
    const float* out_b  = (const float*)d_in[11];

    char* B = (char*)d_ws;
    float*          partials = (float*)(B + 256);                // 64 KB
    float*          xc       = (float*)(B + 65792);              // 8 MB
    unsigned short* x1b      = (unsigned short*)(B + 8454400);   // 4 MB
    unsigned short* x_tb     = (unsigned short*)(B + 12648704);  // 4 MB
    float*          xpad     = (float*)(B + 16843008);           // 14.05 MB
    unsigned short* WcatB    = (unsigned short*)(B + 30890240);  // 28 KB
    float*          bcat     = (float*)(B + 30918912);           // 1 KB
    unsigned short* inpB     = (unsigned short*)(B + 30919936);  // 8 KB
    unsigned short* outB     = (unsigned short*)(B + 30928128);  // 8 KB
    float* out = (float*)d_out;

    k_front<<<8792, 256, 0, stream>>>(x, dw_w, off_w, mask_w, off_b, mask_b,
                                      inp_w, out_w, WcatB, bcat, inpB, outB,
                                      x_tb, xc, partials);
    k_mid<<<512 + 512 + 858, 256, 0, stream>>>(xc, partials, gn_w, gn_b, x1b,
                                               x_tb, inpB, inp_b, xpad);
    k_main<<<8192, 64, 0, stream>>>(x1b, xpad, WcatB, bcat, outB, out_b, out);
}

// Round 7
// 197.722 us; speedup vs baseline: 1.1434x; 1.1434x over previous
//
#include <hip/hip_runtime.h>
#include <math.h>

#define SP 32768            // 32*32*32 voxels
#define PW 38               // padded volume width (zero ring around 34^3 logical)
#define PW2 (PW*PW)         // 1444
#define PVOX (PW*PW*PW)     // 54872

typedef short bf16x8 __attribute__((ext_vector_type(8)));
typedef short s16x4 __attribute__((ext_vector_type(4)));
typedef unsigned short u16x4 __attribute__((ext_vector_type(4)));
typedef float f32x4 __attribute__((ext_vector_type(4)));

__device__ __forceinline__ unsigned short f2b(float f) {
    unsigned u = __float_as_uint(f);
    u = (u + 0x7FFFu + ((u >> 16) & 1u)) >> 16;   // RNE
    return (unsigned short)u;
}
__device__ __forceinline__ f32x4 b2f(u16x4 q) {
    f32x4 r;
    r[0] = __uint_as_float(((unsigned)q[0]) << 16);
    r[1] = __uint_as_float(((unsigned)q[1]) << 16);
    r[2] = __uint_as_float(((unsigned)q[2]) << 16);
    r[3] = __uint_as_float(((unsigned)q[3]) << 16);
    return r;
}

// ================= K1: prep (bf16 B^T weights) + x transpose + dwconv ==============
__global__ void k_front(const float* __restrict__ x, const float* __restrict__ dw,
                        const float* __restrict__ off_w, const float* __restrict__ mask_w,
                        const float* __restrict__ off_b, const float* __restrict__ mask_b,
                        const float* __restrict__ inp_w, const float* __restrict__ out_w,
                        unsigned short* __restrict__ WcatB, float* __restrict__ bcat,
                        unsigned short* __restrict__ inpB, unsigned short* __restrict__ outB,
                        unsigned short* __restrict__ x_tb,
                        float* __restrict__ xc, float* __restrict__ partials) {
    int bb = blockIdx.x, tid = threadIdx.x;
    if (bb < 88) {                               // ---- weight prep ----
        int idx = bb * 256 + tid;
        int j = idx >> 6, k = idx & 63;
        if (j < 224) {
            float v = 0.f;
            if (j < 162) v = off_w[k * 162 + j];
            else if (j < 216) v = mask_w[k * 54 + (j - 162)];
            WcatB[j * 64 + k] = f2b(v);
            if (k == 0) bcat[j] = (j < 162) ? off_b[j] : (j < 216 ? mask_b[j - 162] : 0.f);
        } else if (j < 288) {
            outB[(j - 224) * 64 + k] = f2b(out_w[k * 64 + (j - 224)]);
        } else {
            inpB[(j - 288) * 64 + k] = f2b(inp_w[k * 64 + (j - 288)]);
        }
        return;
    }
    if (bb < 600) {                              // ---- x: NCDHW -> [s][c] bf16 ----
        __shared__ unsigned short tile[64][66];
        int s0 = (bb - 88) * 64;
        int row = tid >> 6, lane = tid & 63;
        for (int c = row; c < 64; c += 4)
            tile[c][lane] = f2b(x[(size_t)c * SP + s0 + lane]);
        __syncthreads();
        for (int r = row; r < 64; r += 4)
            x_tb[(size_t)(s0 + r) * 64 + lane] = tile[lane][r];
        return;
    }
    // ---- depthwise conv 3x3x3 + per-block sum/sumsq ----
    int b3 = bb - 600;
    int e = b3 * 256 + tid;
    int c = e >> 15, s = e & 32767;
    int d = s >> 10, h = (s >> 5) & 31, w = s & 31;
    const float* xs = x + (size_t)c * SP;
    const float* wt = dw + c * 27;
    float a = 0.f;
#pragma unroll
    for (int kd = 0; kd < 3; ++kd) {
        int zz = d + kd - 1; if ((unsigned)zz >= 32u) continue;
#pragma unroll
        for (int kh = 0; kh < 3; ++kh) {
            int yy = h + kh - 1; if ((unsigned)yy >= 32u) continue;
#pragma unroll
            for (int kw = 0; kw < 3; ++kw) {
                int xx = w + kw - 1; if ((unsigned)xx >= 32u) continue;
                a += xs[(zz << 10) + (yy << 5) + xx] * wt[kd * 9 + kh * 3 + kw];
            }
        }
    }
    xc[e] = a;
    __shared__ float rs[256], rq[256];
    rs[tid] = a; rq[tid] = a * a;
    __syncthreads();
    for (int off = 128; off > 0; off >>= 1) {
        if (tid < off) { rs[tid] += rs[tid + off]; rq[tid] += rq[tid + off]; }
        __syncthreads();
    }
    if (tid == 0) {
        partials[b3 * 2 + 0] = rs[0];
        partials[b3 * 2 + 1] = rq[0];
    }
}

// ========= K2: GN+GELU -> x1b  |  MFMA inproj -> xpad (bf16)  |  ring zero =========
__global__ void k_mid(const float* __restrict__ xc, const float* __restrict__ partials,
                      const float* __restrict__ gn_w, const float* __restrict__ gn_b,
                      unsigned short* __restrict__ x1b,
                      const unsigned short* __restrict__ x_tb,
                      const unsigned short* __restrict__ inpB,
                      const float* __restrict__ inp_b,
                      unsigned short* __restrict__ xpad) {
    int bb = blockIdx.x, tid = threadIdx.x;
    if (bb < 512) {                              // ---- GroupNorm(1,C)+GELU, transposed ----
        __shared__ float rs[256], rq[256];
        __shared__ unsigned short tile[64][66];
        float a = 0.f, b = 0.f;
        for (int i = tid; i < 8192; i += 256) { a += partials[2 * i]; b += partials[2 * i + 1]; }
        rs[tid] = a; rq[tid] = b;
        __syncthreads();
        for (int off = 128; off > 0; off >>= 1) {
            if (tid < off) { rs[tid] += rs[tid + off]; rq[tid] += rq[tid + off]; }
            __syncthreads();
        }
        const float Minv = 1.f / 2097152.f;
        float mu = rs[0] * Minv;
        float var = rq[0] * Minv - mu * mu;
        float rsq = rsqrtf(var + 1e-5f);
        int s0 = bb * 64;
        int row = tid >> 6, lane = tid & 63;
        for (int c = row; c < 64; c += 4) {
            float v = (xc[(size_t)c * SP + s0 + lane] - mu) * rsq * gn_w[c] + gn_b[c];
            // gelu(tanh) = v * sigmoid(2t), t = 0.79788456*(v+0.044715 v^3)
            float t2 = 1.5957691216057308f * (v + 0.044715f * v * v * v);
            tile[c][lane] = f2b(v / (1.f + __expf(-t2)));
        }
        __syncthreads();
        for (int r = row; r < 64; r += 4)
            x1b[(size_t)(s0 + r) * 64 + lane] = tile[lane][r];
        return;
    }
    if (bb < 1024) {                             // ---- inproj: 4 waves x 16 voxels ----
        int wv = tid >> 6, lane = tid & 63;
        int quad = lane >> 4, col = lane & 15;
        int s0 = (bb - 512) * 64 + wv * 16;
        bf16x8 a0 = *(const bf16x8*)(x_tb + (size_t)(s0 + col) * 64 + quad * 8);
        bf16x8 a1 = *(const bf16x8*)(x_tb + (size_t)(s0 + col) * 64 + 32 + quad * 8);
        int vp[4];
#pragma unroll
        for (int r = 0; r < 4; ++r) {
            int s = s0 + (quad << 2) + r;        // orig voxel (d,h,w) at 38-coord +2
            vp[r] = (((s >> 10) + 2) * PW + ((s >> 5) & 31) + 2) * PW + (s & 31) + 2;
        }
#pragma unroll
        for (int nt = 0; nt < 4; ++nt) {
            int n0 = nt * 16;
            bf16x8 b0 = *(const bf16x8*)(inpB + (n0 + col) * 64 + quad * 8);
            bf16x8 b1 = *(const bf16x8*)(inpB + (n0 + col) * 64 + 32 + quad * 8);
            f32x4 c = {0.f, 0.f, 0.f, 0.f};
            c = __builtin_amdgcn_mfma_f32_16x16x32_bf16(a0, b0, c, 0, 0, 0);
            c = __builtin_amdgcn_mfma_f32_16x16x32_bf16(a1, b1, c, 0, 0, 0);
            float bq = inp_b[n0 + col];
#pragma unroll
            for (int r = 0; r < 4; ++r)
                xpad[(size_t)vp[r] * 64 + n0 + col] = f2b(c[r] + bq);
        }
        return;
    }
    // ---- ring zero (bf16): 16 voxels x 16 8-byte slots per 256 threads, 4 iters ----
    int cblk = bb - 1024;
    int j = tid >> 4, c4 = tid & 15;
    u16x4 z = {0, 0, 0, 0};
#pragma unroll
    for (int k = 0; k < 4; ++k) {
        int v = cblk * 64 + k * 16 + j;
        if (v >= PVOX) break;
        int zz = v / PW2, r = v - zz * PW2, yy = r / PW, xx = r - yy * PW;
        if (zz < 2 || zz > 33 || yy < 2 || yy > 33 || xx < 2 || xx > 33)
            *(u16x4*)(xpad + (size_t)v * 64 + c4 * 4) = z;
    }
}

// ========= K3: main — 4 waves / 16 voxels per block; no GEMM duplication =========
__global__ void __launch_bounds__(256, 8) k_main(const unsigned short* __restrict__ x1b,
                                                 const unsigned short* __restrict__ xpad,
                                                 const unsigned short* __restrict__ WcatB,
                                                 const float* __restrict__ bcat,
                                                 const unsigned short* __restrict__ outB,
                                                 const float* __restrict__ out_b,
                                                 float* __restrict__ out) {
    __shared__ float om_s[16 * 225];             // offsets+masks; reused as obuf in epilogue
    __shared__ unsigned short smb[16 * 72];      // sampled accum, bf16
    int tid = threadIdx.x, wv = tid >> 6, lane = tid & 63;
    int quad = lane >> 4, col = lane & 15;
    // XCD swizzle: blocks sharing (blk&7) land on one XCD, contiguous 4096-voxel slab
    int sb = ((blockIdx.x & 7) << 8) | (blockIdx.x >> 3);
    int s0 = sb * 16;                            // 16 voxels per block
    // ---- phase 1: offset+mask GEMM (16x64)@(64x224), nt-tiles split across waves ----
    bf16x8 a0 = *(const bf16x8*)(x1b + (size_t)(s0 + col) * 64 + quad * 8);
    bf16x8 a1 = *(const bf16x8*)(x1b + (size_t)(s0 + col) * 64 + 32 + quad * 8);
    for (int jt = wv; jt < 14; jt += 4) {
        int n0 = jt * 16;
        bf16x8 b0 = *(const bf16x8*)(WcatB + (n0 + col) * 64 + quad * 8);
        bf16x8 b1 = *(const bf16x8*)(WcatB + (n0 + col) * 64 + 32 + quad * 8);
        f32x4 c = {0.f, 0.f, 0.f, 0.f};
        c = __builtin_amdgcn_mfma_f32_16x16x32_bf16(a0, b0, c, 0, 0, 0);
        c = __builtin_amdgcn_mfma_f32_16x16x32_bf16(a1, b1, c, 0, 0, 0);
        float bb = bcat[n0 + col];
#pragma unroll
        for (int r = 0; r < 4; ++r)
            om_s[(quad * 4 + r) * 225 + n0 + col] = c[r] + bb;
    }
    __syncthreads();
    // ---- phase 2: softmax over 27 pts, 32 rows = 16 voxels x 2 groups ----
    if (tid < 32) {
        int v = tid >> 1, g = tid & 1;
        float* m = &om_s[v * 225 + 162 + g * 27];
        float mx = m[0];
#pragma unroll
        for (int p = 1; p < 27; ++p) mx = fmaxf(mx, m[p]);
        float e[27]; float sm = 0.f;
#pragma unroll
        for (int p = 0; p < 27; ++p) { e[p] = __expf(m[p] - mx); sm += e[p]; }
        float inv = 1.f / sm;
#pragma unroll
        for (int p = 0; p < 27; ++p) m[p] = e[p] * inv;
    }
    __syncthreads();
    // ---- phase 3: sampling; wave wv handles voxels wv*4..wv*4+3, 4 ch per lane ----
    {
        int v = (wv << 2) + quad, cq = col, gg = col >> 3;
        int sv = s0 + v;
        int d = sv >> 10, h = (sv >> 5) & 31, w = sv & 31;
        float zb = (float)(d + 1), yb = (float)(h + 1), xb = (float)(w + 1);
        const float* orow = &om_s[v * 225 + gg * 81];
        const float* mrow = &om_s[v * 225 + 162 + gg * 27];
        const char* volc = (const char*)xpad + cq * 8;      // 4 bf16 channels
        f32x4 acc = {0.f, 0.f, 0.f, 0.f};
        int p = 0;
        for (int pz = 0; pz < 3; ++pz) {
#pragma unroll
            for (int py = 0; py < 3; ++py) {
#pragma unroll
                for (int px = 0; px < 3; ++px) {
                    float ox = orow[p * 3 + 0], oy = orow[p * 3 + 1], oz = orow[p * 3 + 2];
                    float mk = mrow[p];
                    float ix = __builtin_fmaf(0.25f, ox, xb + (float)px);
                    float iy = __builtin_fmaf(0.5f, oy, yb + (float)py);
                    float iz = __builtin_fmaf(0.5f, oz, zb + (float)pz);
                    // clamp to [0,36]: OOB samples land wholly in the zero ring
                    ix = fminf(fmaxf(ix, 0.f), 36.f);
                    iy = fminf(fmaxf(iy, 0.f), 36.f);
                    iz = fminf(fmaxf(iz, 0.f), 36.f);
                    float xf = floorf(ix), yf = floorf(iy), zf = floorf(iz);
                    float fx = ix - xf, fy = iy - yf, fz = iz - zf;
                    float fi = __builtin_fmaf(zf, (float)PW2, __builtin_fmaf(yf, (float)PW, xf));
                    int ib = ((int)fi) << 7;     // 128 B per voxel row (bf16)
                    f32x4 v000 = b2f(*(const u16x4*)(volc + ib));
                    f32x4 v001 = b2f(*(const u16x4*)(volc + ib + 128));
                    f32x4 v010 = b2f(*(const u16x4*)(volc + ib + PW * 128));
                    f32x4 v011 = b2f(*(const u16x4*)(volc + ib + PW * 128 + 128));
                    f32x4 v100 = b2f(*(const u16x4*)(volc + ib + PW2 * 128));
                    f32x4 v101 = b2f(*(const u16x4*)(volc + ib + PW2 * 128 + 128));
                    f32x4 v110 = b2f(*(const u16x4*)(volc + ib + (PW2 + PW) * 128));
                    f32x4 v111 = b2f(*(const u16x4*)(volc + ib + (PW2 + PW) * 128 + 128));
                    float wz0 = (1.f - fz) * mk, wz1 = fz * mk;
                    float w00 = wz0 * (1.f - fy), w01 = wz0 * fy;
                    float w10 = wz1 * (1.f - fy), w11 = wz1 * fy;
                    f32x4 t00 = v000 + fx * (v001 - v000);
                    f32x4 t01 = v010 + fx * (v011 - v010);
                    f32x4 t10 = v100 + fx * (v101 - v100);
                    f32x4 t11 = v110 + fx * (v111 - v110);
                    acc += w00 * t00 + w01 * t01 + w10 * t10 + w11 * t11;
                    ++p;
                }
            }
        }
        s16x4 sb4;
        sb4[0] = (short)f2b(acc[0]); sb4[1] = (short)f2b(acc[1]);
        sb4[2] = (short)f2b(acc[2]); sb4[3] = (short)f2b(acc[3]);
        *(s16x4*)(smb + v * 72 + cq * 4) = sb4;
    }
    __syncthreads();
    // ---- phase 4: out projection (16x64)@(64x64); wave wv does nt tile wv ----
    {
        float* obuf = om_s;                      // alias: om_s is dead now
        int n0 = wv * 16;
        bf16x8 oa0 = *(const bf16x8*)(smb + col * 72 + quad * 8);
        bf16x8 oa1 = *(const bf16x8*)(smb + col * 72 + 32 + quad * 8);
        bf16x8 b0 = *(const bf16x8*)(outB + (n0 + col) * 64 + quad * 8);
        bf16x8 b1 = *(const bf16x8*)(outB + (n0 + col) * 64 + 32 + quad * 8);
        f32x4 c = {0.f, 0.f, 0.f, 0.f};
        c = __builtin_amdgcn_mfma_f32_16x16x32_bf16(oa0, b0, c, 0, 0, 0);
        c = __builtin_amdgcn_mfma_f32_16x16x32_bf16(oa1, b1, c, 0, 0, 0);
        float bb = out_b[n0 + col];
#pragma unroll
        for (int r = 0; r < 4; ++r)
            obuf[(quad * 4 + r) * 64 + n0 + col] = c[r] + bb;
    }
    __syncthreads();
    // ---- phase 5: coalesced output store (16 rows x 256 B contiguous) ----
    {
        const float* obuf = om_s;
#pragma unroll
        for (int i = 0; i < 4; ++i) {
            int idx = i * 256 + tid;
            out[(size_t)(s0 + (idx >> 6)) * 64 + (idx & 63)] = obuf[idx];
        }
    }
}

extern "C" void kernel_launch(void* const* d_in, const int* in_sizes, int n_in,
                              void* d_out, int out_size, void* d_ws, size_t ws_size,
                              hipStream_t stream) {
    const float* x      = (const float*)d_in[0];
    const float* dw_w   = (const float*)d_in[1];
    const float* gn_w   = (const float*)d_in[2];
    const float* gn_b   = (const float*)d_in[3];
    const float* inp_w  = (const float*)d_in[4];
    const float* inp_b  = (const float*)d_in[5];
    const float* off_w  = (const float*)d_in[6];
    const float* off_b  = (const float*)d_in[7];
    const float* mask_w = (const float*)d_in[8];
    const float* mask_b = (const float*)d_in[9];
    const float* out_w  = (const float*)d_in[10];
    const float* out_b  = (const float*)d_in[11];

    char* B = (char*)d_ws;
    float*          partials = (float*)(B + 256);                // 64 KB
    float*          xc       = (float*)(B + 65792);              // 8 MB
    unsigned short* x1b      = (unsigned short*)(B + 8454400);   // 4 MB
    unsigned short* x_tb     = (unsigned short*)(B + 12648704);  // 4 MB
    unsigned short* xpad     = (unsigned short*)(B + 16843008);  // 7.02 MB (bf16)
    unsigned short* WcatB    = (unsigned short*)(B + 30890240);  // 28 KB
    float*          bcat     = (float*)(B + 30918912);           // 1 KB
    unsigned short* inpB     = (unsigned short*)(B + 30919936);  // 8 KB
    unsigned short* outB     = (unsigned short*)(B + 30928128);  // 8 KB
    float* out = (float*)d_out;

    k_front<<<8792, 256, 0, stream>>>(x, dw_w, off_w, mask_w, off_b, mask_b,
                                      inp_w, out_w, WcatB, bcat, inpB, outB,
                                      x_tb, xc, partials);
    k_mid<<<512 + 512 + 858, 256, 0, stream>>>(xc, partials, gn_w, gn_b, x1b,
                                               x_tb, inpB, inp_b, xpad);
    k_main<<<2048, 256, 0, stream>>>(x1b, xpad, WcatB, bcat, outB, out_b, out);
}